// Round 1
// 8193.243 us; speedup vs baseline: 1.5638x; 1.5638x over previous
//
#include <hip/hip_runtime.h>

typedef unsigned short u16;
typedef __attribute__((ext_vector_type(8))) short s16x8;
typedef __attribute__((ext_vector_type(4))) float f32x4;

#define T_ 64
#define B_ 48
#define H_ 1152
#define E_ 400
#define EPAD 416
#define V_ 32000
#define FOURH 4608
#define TB_ 3072
#define HB (B_*H_)            /* 55296 */
#define LSTRIDE (65*HB)       /* per-layer slot stride in H history */
#define RBLK 512              /* persistent kernel block count */

/* ---- workspace byte offsets (all 256-aligned) ---- */
#define OFF_ZPRE0 ((size_t)0)          /* f32 [3072][4608]  = 56,623,104 B */
#define OFF_HHI   ((size_t)56623104)   /* u16 [3][65][48][1152] = 21,565,440 B */
#define OFF_HLO   ((size_t)78188544)   /* u16 same */
#define OFF_CST   ((size_t)99753984)   /* f32 [3][48][1152] = 663,552 B */
#define OFF_ZH    ((size_t)100417536)  /* u16 [3072][416] = 2,555,904 B */
#define OFF_ZL    ((size_t)102973440)  /* u16 same */
#define OFF_PA    ((size_t)105529344)  /* f32 [3][48][4608] = 2,654,208 B */
#define OFF_PB    ((size_t)108183552)  /* f32 same */
#define OFF_CTR   ((size_t)110837760)  /* int[256] barrier/counters */

__device__ __forceinline__ u16 f2bf(float x) {
    unsigned u = __float_as_uint(x);
    u += 0x7fffu + ((u >> 16) & 1u);      // round-to-nearest-even
    return (u16)(u >> 16);
}
__device__ __forceinline__ float bf2f(u16 h) {
    return __uint_as_float(((unsigned)h) << 16);
}
__device__ __forceinline__ void split8(const float* p, s16x8& hi, s16x8& lo) {
    f32x4 a = *(const f32x4*)(p);
    f32x4 b = *(const f32x4*)(p + 4);
    float v[8];
#pragma unroll
    for (int j = 0; j < 4; ++j) { v[j] = a[j]; v[j + 4] = b[j]; }
#pragma unroll
    for (int j = 0; j < 8; ++j) {
        u16 h = f2bf(v[j]);
        hi[j] = (short)h;
        lo[j] = (short)f2bf(v[j] - bf2f(h));
    }
}
__device__ __forceinline__ f32x4 mfma16(s16x8 a, s16x8 b, f32x4 c) {
    return __builtin_amdgcn_mfma_f32_16x16x32_bf16(a, b, c, 0, 0, 0);
}

/* ---- agent-coherent (sc1, L1/L2-bypass) accessors for cross-block state.
   These keep the read-only weights / A-tiles cacheable in L2: no cache-wide
   wbL2/inv is ever issued, only the small shared state goes through IF. ---- */
__device__ __forceinline__ float ld_sc(const float* p) {
    return __hip_atomic_load(p, __ATOMIC_RELAXED, __HIP_MEMORY_SCOPE_AGENT);
}
__device__ __forceinline__ void st_sc(float* p, float v) {
    __hip_atomic_store(p, v, __ATOMIC_RELAXED, __HIP_MEMORY_SCOPE_AGENT);
}
__device__ __forceinline__ void st_sc16(u16* p, u16 v) {
    __hip_atomic_store(p, v, __ATOMIC_RELAXED, __HIP_MEMORY_SCOPE_AGENT);
}

/* ---------------- device-scope grid barrier (all RBLK blocks co-resident) ----
   No __threadfence (would emit buffer_wbl2 + buffer_inv = full L2 flush per
   stage). All cross-block data is written with sc1 stores (coherent at IF once
   vmcnt drains), so release = s_waitcnt vmcnt(0); acquire needs nothing because
   readers either use sc1 loads (P, C, gen) or first-touch lines (H). -------- */
__device__ __forceinline__ void grid_barrier(int* cnt, int* gen, int nblk) {
    asm volatile("s_waitcnt vmcnt(0)" ::: "memory");  // release: sc1 stores at IF
    __syncthreads();
    if (threadIdx.x == 0) {
        int g = __hip_atomic_load(gen, __ATOMIC_RELAXED, __HIP_MEMORY_SCOPE_AGENT);
        int old = __hip_atomic_fetch_add(cnt, 1, __ATOMIC_RELAXED, __HIP_MEMORY_SCOPE_AGENT);
        if (old == nblk - 1) {
            __hip_atomic_store(cnt, 0, __ATOMIC_RELAXED, __HIP_MEMORY_SCOPE_AGENT);
            asm volatile("s_waitcnt vmcnt(0)" ::: "memory");  // cnt=0 visible before gen++
            __hip_atomic_fetch_add(gen, 1, __ATOMIC_RELAXED, __HIP_MEMORY_SCOPE_AGENT);
        } else {
            while (__hip_atomic_load(gen, __ATOMIC_RELAXED, __HIP_MEMORY_SCOPE_AGENT) == g) {
                __builtin_amdgcn_s_sleep(2);
            }
        }
    }
    __syncthreads();
}

/* ---------------- embedding gather + bf16 hi/lo split ---------------- */
__global__ void gather_split_kernel(const int* __restrict__ x, const float* __restrict__ embW,
                                    u16* __restrict__ Zh, u16* __restrict__ Zl) {
    int i = blockIdx.x * blockDim.x + threadIdx.x;
    const int total = TB_ * EPAD;
    if (i >= total) return;
    int tb = i / EPAD, k = i - tb * EPAD;
    float v = 0.f;
    if (k < E_) v = embW[(size_t)x[tb] * E_ + k];
    u16 h = f2bf(v);
    Zh[i] = h;
    Zl[i] = f2bf(v - bf2f(h));
}

/* ---------------- init h0/c0 into state buffers ---------------- */
__global__ void init_state_kernel(const float* __restrict__ h0, const float* __restrict__ c0,
                                  u16* __restrict__ Hhi, u16* __restrict__ Hlo,
                                  float* __restrict__ Cst) {
    int i = blockIdx.x * blockDim.x + threadIdx.x;
    if (i >= 3 * HB) return;
    int l = i / HB, r = i - l * HB;
    float h = h0[i];
    u16 hh = f2bf(h);
    size_t idx = (size_t)l * LSTRIDE + r;   // slot 0 = t=-1 state
    Hhi[idx] = hh;
    Hlo[idx] = f2bf(h - bf2f(hh));
    Cst[i] = c0[i];
}

/* ---------------- generic big GEMM:  C[M,N] = A(hi/lo bf16)[M,K] * W(f32)[N,K]^T + bias --
   block: 4 waves, tile Mt=192 (wave=48 rows, 3 mtiles) x Nt=128 (8 strips of 16), grid (N/128, M/192) */
__global__ __launch_bounds__(256, 2) void gemm_bias_kernel(
    const u16* __restrict__ Ahi, const u16* __restrict__ Alo, int lda,
    const float* __restrict__ W, int ldw, int kvalid, int ksteps,
    const float* __restrict__ bias1, const float* __restrict__ bias2,
    float* __restrict__ C, int ldc) {
    const int lane = threadIdx.x & 63;
    const int wv = threadIdx.x >> 6;
    const int m16 = lane & 15, q = lane >> 4;
    const int mbase = blockIdx.y * 192 + wv * 48;
    const int nbase = blockIdx.x * 128;

    f32x4 acc[8][3];
#pragma unroll
    for (int s8 = 0; s8 < 8; ++s8)
#pragma unroll
        for (int mt = 0; mt < 3; ++mt) acc[s8][mt] = (f32x4){0.f, 0.f, 0.f, 0.f};

    const u16* arow[3];
    const u16* alrow[3];
#pragma unroll
    for (int mt = 0; mt < 3; ++mt) {
        size_t m = (size_t)(mbase + mt * 16 + m16);
        arow[mt] = Ahi + m * lda + q * 8;
        alrow[mt] = Alo + m * lda + q * 8;
    }
    const float* wrow[8];
#pragma unroll
    for (int s8 = 0; s8 < 8; ++s8) {
        size_t n = (size_t)(nbase + s8 * 16 + m16);
        wrow[s8] = W + n * ldw + q * 8;
    }

    for (int ks = 0; ks < ksteps; ++ks) {
        int k = ks * 32;
        s16x8 ah[3], al[3];
#pragma unroll
        for (int mt = 0; mt < 3; ++mt) {
            ah[mt] = *(const s16x8*)(arow[mt] + k);
            al[mt] = *(const s16x8*)(alrow[mt] + k);
        }
        int kk = k + q * 8;
#pragma unroll
        for (int s8 = 0; s8 < 8; ++s8) {
            s16x8 wh, wl;
            if (kk + 8 <= kvalid) {
                split8(wrow[s8] + k, wh, wl);
            } else {
#pragma unroll
                for (int j = 0; j < 8; ++j) { wh[j] = 0; wl[j] = 0; }
            }
#pragma unroll
            for (int mt = 0; mt < 3; ++mt) {
                acc[s8][mt] = mfma16(ah[mt], wh, acc[s8][mt]);
                acc[s8][mt] = mfma16(ah[mt], wl, acc[s8][mt]);
                acc[s8][mt] = mfma16(al[mt], wh, acc[s8][mt]);
            }
        }
    }
    /* epilogue */
#pragma unroll
    for (int s8 = 0; s8 < 8; ++s8) {
        int n = nbase + s8 * 16 + m16;
        float bv = (bias1 ? bias1[n] : 0.f) + (bias2 ? bias2[n] : 0.f);
#pragma unroll
        for (int mt = 0; mt < 3; ++mt)
#pragma unroll
            for (int r = 0; r < 4; ++r) {
                int m = mbase + mt * 16 + q * 4 + r;
                C[(size_t)m * ldc + n] = acc[s8][mt][r] + bv;
            }
    }
}

/* ---------------- persistent diagonal-wavefront LSTM recurrence ----------------
   66 stages; stage s: layer l at t=s-l. GEMM phase (tasks of 16 N-cols x 48 M x K=1152)
   then gates phase, separated by grid barriers.
   Coherence scheme (no cache-wide invalidation):
     - P (Pa/Pb), Cst : sc1 atomics both ways (addresses reused every stage, read-once)
     - H history      : sc1 stores; PLAIN cached reads (each slot is written once and
                        read only in the following stage -> reader XCD first-touch,
                        no stale L1/L2 copy can exist within this kernel)
     - weights/Zpre0  : plain reads, stay L2-resident across stages  */
__global__ __launch_bounds__(256, 2) void recur_kernel(
    const float* __restrict__ Wh0, const float* __restrict__ Wi1, const float* __restrict__ Wh1,
    const float* __restrict__ Wi2, const float* __restrict__ Wh2,
    const float* __restrict__ bi0, const float* __restrict__ bh0,
    const float* __restrict__ bi1, const float* __restrict__ bh1,
    const float* __restrict__ bi2, const float* __restrict__ bh2,
    const float* __restrict__ Zpre0, u16* __restrict__ Hhi, u16* __restrict__ Hlo,
    float* __restrict__ Cst, float* __restrict__ Pa, float* __restrict__ Pb,
    int* __restrict__ ctrs, float* __restrict__ out_h, float* __restrict__ out_c) {
    const int lane = threadIdx.x & 63;
    const int slot = threadIdx.x >> 6;  // wave in block
    const int blk = blockIdx.x;
    const int m16 = lane & 15, q = lane >> 4;
    int* cnt = ctrs + 0;
    int* gen = ctrs + 1;

    for (int s = 0; s < 66; ++s) {
        const int t0 = s, t1 = s - 1, t2 = s - 2;
        /* ---- GEMM phase: units u = (layer,part) ---- */
        int units[5];
        int nu = 0;
        if (t0 >= 0 && t0 < 64) units[nu++] = 0;                       // l0 h-part
        if (t1 >= 0 && t1 < 64) { units[nu++] = 1; units[nu++] = 2; }  // l1 z,h
        if (t2 >= 0 && t2 < 64) { units[nu++] = 3; units[nu++] = 4; }  // l2 z,h
        const int ntasks = nu * 288;
        const int jj = (slot - blk) & 3;
        const int task = jj * RBLK + blk;   // each (block,wave) -> <=1 task, spread over CUs
        if (task < ntasks) {
            const int u = units[task / 288];
            const int strip = task % 288;
            const int n0 = strip * 16;
            int tt;
            size_t aoff;
            const float* W;
            float* Pout;
            bool initZ = false;
            switch (u) {
                case 0: tt = t0; W = Wh0; aoff = (size_t)tt * HB;                 Pout = Pa;                       initZ = true; break;
                case 1: tt = t1; W = Wi1; aoff = (size_t)(tt + 1) * HB;           Pout = Pa + (size_t)B_ * FOURH;  break;
                case 2: tt = t1; W = Wh1; aoff = LSTRIDE + (size_t)tt * HB;       Pout = Pb + (size_t)B_ * FOURH;  break;
                case 3: tt = t2; W = Wi2; aoff = LSTRIDE + (size_t)(tt + 1) * HB; Pout = Pa + 2 * (size_t)B_ * FOURH; break;
                default: tt = t2; W = Wh2; aoff = 2 * (size_t)LSTRIDE + (size_t)tt * HB; Pout = Pb + 2 * (size_t)B_ * FOURH; break;
            }
            f32x4 acc[3];
            if (initZ) {
                const float* zp = Zpre0 + (size_t)(tt * B_) * FOURH + n0 + m16;
#pragma unroll
                for (int mt = 0; mt < 3; ++mt)
#pragma unroll
                    for (int r = 0; r < 4; ++r)
                        acc[mt][r] = zp[(size_t)(mt * 16 + q * 4 + r) * FOURH];
            } else {
#pragma unroll
                for (int mt = 0; mt < 3; ++mt) acc[mt] = (f32x4){0.f, 0.f, 0.f, 0.f};
            }
            const float* wrow = W + (size_t)(n0 + m16) * H_ + q * 8;
            const u16* arow[3];
            const u16* alrow[3];
#pragma unroll
            for (int mt = 0; mt < 3; ++mt) {
                size_t ro = aoff + (size_t)(mt * 16 + m16) * H_ + q * 8;
                arow[mt] = Hhi + ro;
                alrow[mt] = Hlo + ro;
            }
#pragma unroll 2
            for (int ks = 0; ks < 36; ++ks) {
                int k = ks * 32;
                s16x8 wh, wl;
                split8(wrow + k, wh, wl);
#pragma unroll
                for (int mt = 0; mt < 3; ++mt) {
                    s16x8 ah = *(const s16x8*)(arow[mt] + k);
                    s16x8 al = *(const s16x8*)(alrow[mt] + k);
                    acc[mt] = mfma16(ah, wh, acc[mt]);
                    acc[mt] = mfma16(ah, wl, acc[mt]);
                    acc[mt] = mfma16(al, wh, acc[mt]);
                }
            }
            float* pout = Pout + n0 + m16;
#pragma unroll
            for (int mt = 0; mt < 3; ++mt)
#pragma unroll
                for (int r = 0; r < 4; ++r)
                    st_sc(pout + (size_t)(mt * 16 + q * 4 + r) * FOURH, acc[mt][r]);
        }
        grid_barrier(cnt, gen, RBLK);

        /* ---- gates phase ---- */
        int actl[3];
        int nl = 0;
        if (t0 >= 0 && t0 < 64) actl[nl++] = 0;
        if (t1 >= 0 && t1 < 64) actl[nl++] = 1;
        if (t2 >= 0 && t2 < 64) actl[nl++] = 2;
        const int nitems = nl * HB;
        for (int i = blk * 256 + threadIdx.x; i < nitems; i += RBLK * 256) {
            int li = i / HB, r = i - li * HB;
            int l = actl[li];
            int tt = s - l;
            int b = r / H_, j = r - b * H_;
            const float* pa = Pa + (size_t)l * B_ * FOURH + (size_t)b * FOURH;
            float pi = ld_sc(pa + j), pf = ld_sc(pa + H_ + j);
            float po = ld_sc(pa + 2 * H_ + j), pg = ld_sc(pa + 3 * H_ + j);
            if (l > 0) {
                const float* pb = Pb + (size_t)l * B_ * FOURH + (size_t)b * FOURH;
                pi += ld_sc(pb + j); pf += ld_sc(pb + H_ + j);
                po += ld_sc(pb + 2 * H_ + j); pg += ld_sc(pb + 3 * H_ + j);
            }
            const float* bi = (l == 0) ? bi0 : (l == 1) ? bi1 : bi2;
            const float* bh = (l == 0) ? bh0 : (l == 1) ? bh1 : bh2;
            pi += bi[j] + bh[j];
            pf += bi[H_ + j] + bh[H_ + j];
            po += bi[2 * H_ + j] + bh[2 * H_ + j];
            pg += bi[3 * H_ + j] + bh[3 * H_ + j];
            float c = ld_sc(Cst + l * HB + r);
            float ig = 1.f / (1.f + expf(-pi));
            float fg = 1.f / (1.f + expf(-pf));
            float og = 1.f / (1.f + expf(-po));
            float gg = tanhf(pg);
            float cn = fg * c + ig * gg;
            float hn = og * tanhf(cn);
            st_sc(Cst + l * HB + r, cn);
            u16 hh = f2bf(hn);
            size_t hidx = (size_t)l * LSTRIDE + (size_t)(tt + 1) * HB + r;
            st_sc16(Hhi + hidx, hh);
            st_sc16(Hlo + hidx, f2bf(hn - bf2f(hh)));
            if (tt == 63) {
                out_h[l * HB + r] = hn;
                out_c[l * HB + r] = cn;
            }
        }
        grid_barrier(cnt, gen, RBLK);
    }
}

extern "C" void kernel_launch(void* const* d_in, const int* in_sizes, int n_in,
                              void* d_out, int out_size, void* d_ws, size_t ws_size,
                              hipStream_t stream) {
    (void)in_sizes; (void)n_in; (void)out_size; (void)ws_size;
    const int* x = (const int*)d_in[0];
    const float* h0 = (const float*)d_in[1];
    const float* c0 = (const float*)d_in[2];
    const float* embW = (const float*)d_in[3];
    const float* Wi0 = (const float*)d_in[4];
    const float* bi0 = (const float*)d_in[5];
    const float* Wh0 = (const float*)d_in[6];
    const float* bh0 = (const float*)d_in[7];
    const float* Wi1 = (const float*)d_in[8];
    const float* bi1 = (const float*)d_in[9];
    const float* Wh1 = (const float*)d_in[10];
    const float* bh1 = (const float*)d_in[11];
    const float* Wi2 = (const float*)d_in[12];
    const float* bi2 = (const float*)d_in[13];
    const float* Wh2 = (const float*)d_in[14];
    const float* bh2 = (const float*)d_in[15];
    const float* Wdec = (const float*)d_in[16];
    const float* bdec = (const float*)d_in[17];

    char* ws = (char*)d_ws;
    float* Zpre0 = (float*)(ws + OFF_ZPRE0);
    u16* Hhi = (u16*)(ws + OFF_HHI);
    u16* Hlo = (u16*)(ws + OFF_HLO);
    float* Cst = (float*)(ws + OFF_CST);
    u16* Zh = (u16*)(ws + OFF_ZH);
    u16* Zl = (u16*)(ws + OFF_ZL);
    float* Pa = (float*)(ws + OFF_PA);
    float* Pb = (float*)(ws + OFF_PB);
    int* ctrs = (int*)(ws + OFF_CTR);

    float* decoded = (float*)d_out;
    float* out_h = decoded + (size_t)TB_ * V_;
    float* out_c = out_h + 3 * (size_t)HB;

    hipMemsetAsync(ctrs, 0, 256 * sizeof(int), stream);
    gather_split_kernel<<<(TB_ * EPAD + 255) / 256, 256, 0, stream>>>(x, embW, Zh, Zl);
    init_state_kernel<<<(3 * HB + 255) / 256, 256, 0, stream>>>(h0, c0, Hhi, Hlo, Cst);

    /* phase A: Zpre0 = emb @ Wi0^T (no bias; biases added in gates) */
    dim3 gA(FOURH / 128, TB_ / 192);  // 36 x 16
    gemm_bias_kernel<<<gA, 256, 0, stream>>>(Zh, Zl, EPAD, Wi0, E_, E_, (E_ + 31) / 32,
                                             nullptr, nullptr, Zpre0, FOURH);

    /* recurrence: 66 diagonal stages, persistent kernel */
    recur_kernel<<<RBLK, 256, 0, stream>>>(Wh0, Wi1, Wh1, Wi2, Wh2,
                                           bi0, bh0, bi1, bh1, bi2, bh2,
                                           Zpre0, Hhi, Hlo, Cst, Pa, Pb, ctrs, out_h, out_c);

    /* decode: decoded = out @ Wdec^T + bdec ; A = h2 history slots 1..64 */
    dim3 gD(V_ / 128, TB_ / 192);  // 250 x 16
    gemm_bias_kernel<<<gD, 256, 0, stream>>>(Hhi + (size_t)(2 * 65 + 1) * HB,
                                             Hlo + (size_t)(2 * 65 + 1) * HB, H_,
                                             Wdec, H_, H_, H_ / 32,
                                             bdec, nullptr, decoded, V_);
}

// Round 2
// 7695.190 us; speedup vs baseline: 1.6651x; 1.0647x over previous
//
#include <hip/hip_runtime.h>

typedef unsigned short u16;
typedef __attribute__((ext_vector_type(8))) short s16x8;
typedef __attribute__((ext_vector_type(4))) float f32x4;

#define T_ 64
#define B_ 48
#define H_ 1152
#define E_ 400
#define EPAD 416
#define V_ 32000
#define FOURH 4608
#define TB_ 3072
#define HB (B_*H_)            /* 55296 */
#define LSTRIDE (65*HB)       /* per-layer slot stride in H history */
#define RBLK 1024             /* persistent kernel block count (4/CU) */
#define PSZ ((size_t)(3*B_*FOURH))  /* floats per P partial buffer = 663,552 */

/* ---- workspace byte offsets (all 256-aligned) ---- */
#define OFF_ZPRE0 ((size_t)0)          /* f32 [3072][4608]  = 56,623,104 B */
#define OFF_HHI   ((size_t)56623104)   /* u16 [3][65][48][1152] = 21,565,440 B */
#define OFF_HLO   ((size_t)78188544)   /* u16 same */
#define OFF_CST   ((size_t)99753984)   /* f32 [3][48][1152] = 663,552 B */
#define OFF_ZH    ((size_t)100417536)  /* u16 [3072][416] = 2,555,904 B */
#define OFF_ZL    ((size_t)102973440)  /* u16 same */
#define OFF_P0    ((size_t)105529344)  /* 4 x f32 [3][48][4608] partial buffers */
#define OFF_CTR   ((size_t)116146176)  /* int[256] barrier/counters */

__device__ __forceinline__ u16 f2bf(float x) {
    unsigned u = __float_as_uint(x);
    u += 0x7fffu + ((u >> 16) & 1u);      // round-to-nearest-even
    return (u16)(u >> 16);
}
__device__ __forceinline__ float bf2f(u16 h) {
    return __uint_as_float(((unsigned)h) << 16);
}
__device__ __forceinline__ void split8(const float* p, s16x8& hi, s16x8& lo) {
    f32x4 a = *(const f32x4*)(p);
    f32x4 b = *(const f32x4*)(p + 4);
    float v[8];
#pragma unroll
    for (int j = 0; j < 4; ++j) { v[j] = a[j]; v[j + 4] = b[j]; }
#pragma unroll
    for (int j = 0; j < 8; ++j) {
        u16 h = f2bf(v[j]);
        hi[j] = (short)h;
        lo[j] = (short)f2bf(v[j] - bf2f(h));
    }
}
__device__ __forceinline__ void split8r(f32x4 a, f32x4 b, s16x8& hi, s16x8& lo) {
    float v[8];
#pragma unroll
    for (int j = 0; j < 4; ++j) { v[j] = a[j]; v[j + 4] = b[j]; }
#pragma unroll
    for (int j = 0; j < 8; ++j) {
        u16 h = f2bf(v[j]);
        hi[j] = (short)h;
        lo[j] = (short)f2bf(v[j] - bf2f(h));
    }
}
__device__ __forceinline__ f32x4 mfma16(s16x8 a, s16x8 b, f32x4 c) {
    return __builtin_amdgcn_mfma_f32_16x16x32_bf16(a, b, c, 0, 0, 0);
}

/* ---- agent-coherent (sc1, L1/L2-bypass) accessors for cross-block state. ---- */
__device__ __forceinline__ float ld_sc(const float* p) {
    return __hip_atomic_load(p, __ATOMIC_RELAXED, __HIP_MEMORY_SCOPE_AGENT);
}
__device__ __forceinline__ void st_sc(float* p, float v) {
    __hip_atomic_store(p, v, __ATOMIC_RELAXED, __HIP_MEMORY_SCOPE_AGENT);
}
__device__ __forceinline__ void st_sc16(u16* p, u16 v) {
    __hip_atomic_store(p, v, __ATOMIC_RELAXED, __HIP_MEMORY_SCOPE_AGENT);
}

/* ---------------- two-level device-scope grid barrier ----------------
   16 group counters (64B apart) + root + gen. No cache-wide flush: release =
   s_waitcnt vmcnt(0) (all cross-block data uses sc1 ops, coherent at IF).
   Reset-before-parent-increment ordering makes counters reusable across
   consecutive barriers (blocks only re-arrive after gen bumps). ---- */
__device__ __forceinline__ void grid_barrier(int* ctrs, int nblk) {
    asm volatile("s_waitcnt vmcnt(0)" ::: "memory");  // release: sc1 stores at IF
    __syncthreads();
    if (threadIdx.x == 0) {
        int* gen = ctrs + 252;
        int* root = ctrs + 248;
        int* gcnt = ctrs + ((blockIdx.x & 15) << 4);
        const int gsz = nblk >> 4;
        int g = __hip_atomic_load(gen, __ATOMIC_RELAXED, __HIP_MEMORY_SCOPE_AGENT);
        int old = __hip_atomic_fetch_add(gcnt, 1, __ATOMIC_RELAXED, __HIP_MEMORY_SCOPE_AGENT);
        if (old == gsz - 1) {
            __hip_atomic_store(gcnt, 0, __ATOMIC_RELAXED, __HIP_MEMORY_SCOPE_AGENT);
            asm volatile("s_waitcnt vmcnt(0)" ::: "memory");
            int r = __hip_atomic_fetch_add(root, 1, __ATOMIC_RELAXED, __HIP_MEMORY_SCOPE_AGENT);
            if (r == 15) {
                __hip_atomic_store(root, 0, __ATOMIC_RELAXED, __HIP_MEMORY_SCOPE_AGENT);
                asm volatile("s_waitcnt vmcnt(0)" ::: "memory");
                __hip_atomic_fetch_add(gen, 1, __ATOMIC_RELAXED, __HIP_MEMORY_SCOPE_AGENT);
            }
        }
        while (__hip_atomic_load(gen, __ATOMIC_RELAXED, __HIP_MEMORY_SCOPE_AGENT) == g) {
            __builtin_amdgcn_s_sleep(4);
        }
    }
    __syncthreads();
}

/* ---------------- embedding gather + bf16 hi/lo split ---------------- */
__global__ void gather_split_kernel(const int* __restrict__ x, const float* __restrict__ embW,
                                    u16* __restrict__ Zh, u16* __restrict__ Zl) {
    int i = blockIdx.x * blockDim.x + threadIdx.x;
    const int total = TB_ * EPAD;
    if (i >= total) return;
    int tb = i / EPAD, k = i - tb * EPAD;
    float v = 0.f;
    if (k < E_) v = embW[(size_t)x[tb] * E_ + k];
    u16 h = f2bf(v);
    Zh[i] = h;
    Zl[i] = f2bf(v - bf2f(h));
}

/* ---------------- init h0/c0 into state buffers ---------------- */
__global__ void init_state_kernel(const float* __restrict__ h0, const float* __restrict__ c0,
                                  u16* __restrict__ Hhi, u16* __restrict__ Hlo,
                                  float* __restrict__ Cst) {
    int i = blockIdx.x * blockDim.x + threadIdx.x;
    if (i >= 3 * HB) return;
    int l = i / HB, r = i - l * HB;
    float h = h0[i];
    u16 hh = f2bf(h);
    size_t idx = (size_t)l * LSTRIDE + r;   // slot 0 = t=-1 state
    Hhi[idx] = hh;
    Hlo[idx] = f2bf(h - bf2f(hh));
    Cst[i] = c0[i];
}

/* ---------------- generic big GEMM (phase A + decode, unchanged) ---------------- */
__global__ __launch_bounds__(256, 2) void gemm_bias_kernel(
    const u16* __restrict__ Ahi, const u16* __restrict__ Alo, int lda,
    const float* __restrict__ W, int ldw, int kvalid, int ksteps,
    const float* __restrict__ bias1, const float* __restrict__ bias2,
    float* __restrict__ C, int ldc) {
    const int lane = threadIdx.x & 63;
    const int wv = threadIdx.x >> 6;
    const int m16 = lane & 15, q = lane >> 4;
    const int mbase = blockIdx.y * 192 + wv * 48;
    const int nbase = blockIdx.x * 128;

    f32x4 acc[8][3];
#pragma unroll
    for (int s8 = 0; s8 < 8; ++s8)
#pragma unroll
        for (int mt = 0; mt < 3; ++mt) acc[s8][mt] = (f32x4){0.f, 0.f, 0.f, 0.f};

    const u16* arow[3];
    const u16* alrow[3];
#pragma unroll
    for (int mt = 0; mt < 3; ++mt) {
        size_t m = (size_t)(mbase + mt * 16 + m16);
        arow[mt] = Ahi + m * lda + q * 8;
        alrow[mt] = Alo + m * lda + q * 8;
    }
    const float* wrow[8];
#pragma unroll
    for (int s8 = 0; s8 < 8; ++s8) {
        size_t n = (size_t)(nbase + s8 * 16 + m16);
        wrow[s8] = W + n * ldw + q * 8;
    }

    for (int ks = 0; ks < ksteps; ++ks) {
        int k = ks * 32;
        s16x8 ah[3], al[3];
#pragma unroll
        for (int mt = 0; mt < 3; ++mt) {
            ah[mt] = *(const s16x8*)(arow[mt] + k);
            al[mt] = *(const s16x8*)(alrow[mt] + k);
        }
        int kk = k + q * 8;
#pragma unroll
        for (int s8 = 0; s8 < 8; ++s8) {
            s16x8 wh, wl;
            if (kk + 8 <= kvalid) {
                split8(wrow[s8] + k, wh, wl);
            } else {
#pragma unroll
                for (int j = 0; j < 8; ++j) { wh[j] = 0; wl[j] = 0; }
            }
#pragma unroll
            for (int mt = 0; mt < 3; ++mt) {
                acc[s8][mt] = mfma16(ah[mt], wh, acc[s8][mt]);
                acc[s8][mt] = mfma16(ah[mt], wl, acc[s8][mt]);
                acc[s8][mt] = mfma16(al[mt], wh, acc[s8][mt]);
            }
        }
    }
    /* epilogue */
#pragma unroll
    for (int s8 = 0; s8 < 8; ++s8) {
        int n = nbase + s8 * 16 + m16;
        float bv = (bias1 ? bias1[n] : 0.f) + (bias2 ? bias2[n] : 0.f);
#pragma unroll
        for (int mt = 0; mt < 3; ++mt)
#pragma unroll
            for (int r = 0; r < 4; ++r) {
                int m = mbase + mt * 16 + q * 4 + r;
                C[(size_t)m * ldc + n] = acc[s8][mt][r] + bv;
            }
    }
}

/* ---------------- persistent diagonal-wavefront LSTM recurrence ----------------
   66 stages; stage s: layer l at t=s-l. K-SPLIT GEMM phase: tasks of
   (unit, strip, khalf): 16 N-cols x 48 M x K=576. Partials go to 4 buffers
   P[z|h][kh0|kh1]; gates phase sums them. More, shorter tasks -> ~11 active
   waves/CU instead of 5.6 (latency hiding for the L3-miss weight stream),
   plus depth-2 register prefetch of the weight stream. */
__global__ __launch_bounds__(256, 4) void recur_kernel(
    const float* __restrict__ Wh0, const float* __restrict__ Wi1, const float* __restrict__ Wh1,
    const float* __restrict__ Wi2, const float* __restrict__ Wh2,
    const float* __restrict__ bi0, const float* __restrict__ bh0,
    const float* __restrict__ bi1, const float* __restrict__ bh1,
    const float* __restrict__ bi2, const float* __restrict__ bh2,
    const float* __restrict__ Zpre0, u16* __restrict__ Hhi, u16* __restrict__ Hlo,
    float* __restrict__ Cst, float* __restrict__ P0,
    int* __restrict__ ctrs, float* __restrict__ out_h, float* __restrict__ out_c) {
    const int lane = threadIdx.x & 63;
    const int slot = threadIdx.x >> 6;  // wave in block
    const int blk = blockIdx.x;
    const int m16 = lane & 15, q = lane >> 4;

    for (int s = 0; s < 66; ++s) {
        const int t0 = s, t1 = s - 1, t2 = s - 2;
        /* ---- GEMM phase: tasks = (unit, strip, khalf) ---- */
        int units[5];
        int nu = 0;
        if (t0 >= 0 && t0 < 64) units[nu++] = 0;                       // l0 h-part
        if (t1 >= 0 && t1 < 64) { units[nu++] = 1; units[nu++] = 2; }  // l1 z,h
        if (t2 >= 0 && t2 < 64) { units[nu++] = 3; units[nu++] = 4; }  // l2 z,h
        const int ntasks = nu * 576;
        const int jj = (slot - blk) & 3;
        const int task = jj * RBLK + blk;   // each (block,wave) -> <=1 task
        if (task < ntasks) {
            const int u = units[task / 576];
            const int rem = task % 576;
            const int kh = rem & 1;
            const int strip = rem >> 1;
            const int n0 = strip * 16;
            const int koff = kh * 576;
            int tt;
            size_t aoff;
            const float* W;
            float* Pout;
            bool initZ = false;
            switch (u) {
                case 0: tt = t0; W = Wh0; aoff = (size_t)tt * HB;
                        Pout = P0 + 2 * PSZ;                          initZ = (kh == 0); break;
                case 1: tt = t1; W = Wi1; aoff = (size_t)(tt + 1) * HB;
                        Pout = P0 + (size_t)B_ * FOURH;               break;
                case 2: tt = t1; W = Wh1; aoff = LSTRIDE + (size_t)tt * HB;
                        Pout = P0 + 2 * PSZ + (size_t)B_ * FOURH;     break;
                case 3: tt = t2; W = Wi2; aoff = LSTRIDE + (size_t)(tt + 1) * HB;
                        Pout = P0 + 2 * (size_t)B_ * FOURH;           break;
                default: tt = t2; W = Wh2; aoff = 2 * (size_t)LSTRIDE + (size_t)tt * HB;
                        Pout = P0 + 2 * PSZ + 2 * (size_t)B_ * FOURH; break;
            }
            if (kh) Pout += PSZ;
            f32x4 acc[3];
            if (initZ) {
                const float* zp = Zpre0 + (size_t)(tt * B_) * FOURH + n0 + m16;
#pragma unroll
                for (int mt = 0; mt < 3; ++mt)
#pragma unroll
                    for (int r = 0; r < 4; ++r)
                        acc[mt][r] = zp[(size_t)(mt * 16 + q * 4 + r) * FOURH];
            } else {
#pragma unroll
                for (int mt = 0; mt < 3; ++mt) acc[mt] = (f32x4){0.f, 0.f, 0.f, 0.f};
            }
            const float* wrow = W + (size_t)(n0 + m16) * H_ + koff + q * 8;
            const u16* arow[3];
            const u16* alrow[3];
#pragma unroll
            for (int mt = 0; mt < 3; ++mt) {
                size_t ro = aoff + (size_t)(mt * 16 + m16) * H_ + koff + q * 8;
                arow[mt] = Hhi + ro;
                alrow[mt] = Hlo + ro;
            }
            /* software pipeline: weights depth-2, A depth-1 (A is L2-hot) */
            f32x4 w0A = *(const f32x4*)(wrow);
            f32x4 w0B = *(const f32x4*)(wrow + 4);
            f32x4 w1A = *(const f32x4*)(wrow + 32);
            f32x4 w1B = *(const f32x4*)(wrow + 36);
            s16x8 ah[3], al[3];
#pragma unroll
            for (int mt = 0; mt < 3; ++mt) {
                ah[mt] = *(const s16x8*)(arow[mt]);
                al[mt] = *(const s16x8*)(alrow[mt]);
            }
#pragma unroll 2
            for (int ks = 0; ks < 18; ++ks) {
                int kp1 = ks + 1; if (kp1 > 17) kp1 = 17;
                int kp2 = ks + 2; if (kp2 > 17) kp2 = 17;
                const int kn1 = kp1 * 32, kn2 = kp2 * 32;
                f32x4 w2A = *(const f32x4*)(wrow + kn2);
                f32x4 w2B = *(const f32x4*)(wrow + kn2 + 4);
                s16x8 nah[3], nal[3];
#pragma unroll
                for (int mt = 0; mt < 3; ++mt) {
                    nah[mt] = *(const s16x8*)(arow[mt] + kn1);
                    nal[mt] = *(const s16x8*)(alrow[mt] + kn1);
                }
                s16x8 wh, wl;
                split8r(w0A, w0B, wh, wl);
#pragma unroll
                for (int mt = 0; mt < 3; ++mt) {
                    acc[mt] = mfma16(ah[mt], wh, acc[mt]);
                    acc[mt] = mfma16(ah[mt], wl, acc[mt]);
                    acc[mt] = mfma16(al[mt], wh, acc[mt]);
                }
                w0A = w1A; w0B = w1B; w1A = w2A; w1B = w2B;
#pragma unroll
                for (int mt = 0; mt < 3; ++mt) { ah[mt] = nah[mt]; al[mt] = nal[mt]; }
            }
            float* pout = Pout + n0 + m16;
#pragma unroll
            for (int mt = 0; mt < 3; ++mt)
#pragma unroll
                for (int r = 0; r < 4; ++r)
                    st_sc(pout + (size_t)(mt * 16 + q * 4 + r) * FOURH, acc[mt][r]);
        }
        grid_barrier(ctrs, RBLK);

        /* ---- gates phase: pre = (l>0 ? Pz0+Pz1 : 0) + Ph0 + Ph1 + biases ---- */
        int actl[3];
        int nl = 0;
        if (t0 >= 0 && t0 < 64) actl[nl++] = 0;
        if (t1 >= 0 && t1 < 64) actl[nl++] = 1;
        if (t2 >= 0 && t2 < 64) actl[nl++] = 2;
        const int nitems = nl * HB;
        for (int i = blk * 256 + threadIdx.x; i < nitems; i += RBLK * 256) {
            int li = i / HB, r = i - li * HB;
            int l = actl[li];
            int tt = s - l;
            int b = r / H_, j = r - b * H_;
            const float* p2 = P0 + 2 * PSZ + (size_t)l * B_ * FOURH + (size_t)b * FOURH;
            const float* p3 = p2 + PSZ;
            float pi = ld_sc(p2 + j) + ld_sc(p3 + j);
            float pf = ld_sc(p2 + H_ + j) + ld_sc(p3 + H_ + j);
            float po = ld_sc(p2 + 2 * H_ + j) + ld_sc(p3 + 2 * H_ + j);
            float pg = ld_sc(p2 + 3 * H_ + j) + ld_sc(p3 + 3 * H_ + j);
            if (l > 0) {
                const float* pz0 = P0 + (size_t)l * B_ * FOURH + (size_t)b * FOURH;
                const float* pz1 = pz0 + PSZ;
                pi += ld_sc(pz0 + j) + ld_sc(pz1 + j);
                pf += ld_sc(pz0 + H_ + j) + ld_sc(pz1 + H_ + j);
                po += ld_sc(pz0 + 2 * H_ + j) + ld_sc(pz1 + 2 * H_ + j);
                pg += ld_sc(pz0 + 3 * H_ + j) + ld_sc(pz1 + 3 * H_ + j);
            }
            const float* bi = (l == 0) ? bi0 : (l == 1) ? bi1 : bi2;
            const float* bh = (l == 0) ? bh0 : (l == 1) ? bh1 : bh2;
            pi += bi[j] + bh[j];
            pf += bi[H_ + j] + bh[H_ + j];
            po += bi[2 * H_ + j] + bh[2 * H_ + j];
            pg += bi[3 * H_ + j] + bh[3 * H_ + j];
            float c = ld_sc(Cst + l * HB + r);
            float ig = 1.f / (1.f + expf(-pi));
            float fg = 1.f / (1.f + expf(-pf));
            float og = 1.f / (1.f + expf(-po));
            float gg = tanhf(pg);
            float cn = fg * c + ig * gg;
            float hn = og * tanhf(cn);
            st_sc(Cst + l * HB + r, cn);
            u16 hh = f2bf(hn);
            size_t hidx = (size_t)l * LSTRIDE + (size_t)(tt + 1) * HB + r;
            st_sc16(Hhi + hidx, hh);
            st_sc16(Hlo + hidx, f2bf(hn - bf2f(hh)));
            if (tt == 63) {
                out_h[l * HB + r] = hn;
                out_c[l * HB + r] = cn;
            }
        }
        grid_barrier(ctrs, RBLK);
    }
}

extern "C" void kernel_launch(void* const* d_in, const int* in_sizes, int n_in,
                              void* d_out, int out_size, void* d_ws, size_t ws_size,
                              hipStream_t stream) {
    (void)in_sizes; (void)n_in; (void)out_size; (void)ws_size;
    const int* x = (const int*)d_in[0];
    const float* h0 = (const float*)d_in[1];
    const float* c0 = (const float*)d_in[2];
    const float* embW = (const float*)d_in[3];
    const float* Wi0 = (const float*)d_in[4];
    const float* bi0 = (const float*)d_in[5];
    const float* Wh0 = (const float*)d_in[6];
    const float* bh0 = (const float*)d_in[7];
    const float* Wi1 = (const float*)d_in[8];
    const float* bi1 = (const float*)d_in[9];
    const float* Wh1 = (const float*)d_in[10];
    const float* bh1 = (const float*)d_in[11];
    const float* Wi2 = (const float*)d_in[12];
    const float* bi2 = (const float*)d_in[13];
    const float* Wh2 = (const float*)d_in[14];
    const float* bh2 = (const float*)d_in[15];
    const float* Wdec = (const float*)d_in[16];
    const float* bdec = (const float*)d_in[17];

    char* ws = (char*)d_ws;
    float* Zpre0 = (float*)(ws + OFF_ZPRE0);
    u16* Hhi = (u16*)(ws + OFF_HHI);
    u16* Hlo = (u16*)(ws + OFF_HLO);
    float* Cst = (float*)(ws + OFF_CST);
    u16* Zh = (u16*)(ws + OFF_ZH);
    u16* Zl = (u16*)(ws + OFF_ZL);
    float* P0 = (float*)(ws + OFF_P0);
    int* ctrs = (int*)(ws + OFF_CTR);

    float* decoded = (float*)d_out;
    float* out_h = decoded + (size_t)TB_ * V_;
    float* out_c = out_h + 3 * (size_t)HB;

    hipMemsetAsync(ctrs, 0, 256 * sizeof(int), stream);
    gather_split_kernel<<<(TB_ * EPAD + 255) / 256, 256, 0, stream>>>(x, embW, Zh, Zl);
    init_state_kernel<<<(3 * HB + 255) / 256, 256, 0, stream>>>(h0, c0, Hhi, Hlo, Cst);

    /* phase A: Zpre0 = emb @ Wi0^T (no bias; biases added in gates) */
    dim3 gA(FOURH / 128, TB_ / 192);  // 36 x 16
    gemm_bias_kernel<<<gA, 256, 0, stream>>>(Zh, Zl, EPAD, Wi0, E_, E_, (E_ + 31) / 32,
                                             nullptr, nullptr, Zpre0, FOURH);

    /* recurrence: 66 diagonal stages, persistent kernel */
    recur_kernel<<<RBLK, 256, 0, stream>>>(Wh0, Wi1, Wh1, Wi2, Wh2,
                                           bi0, bh0, bi1, bh1, bi2, bh2,
                                           Zpre0, Hhi, Hlo, Cst, P0, ctrs, out_h, out_c);

    /* decode: decoded = out @ Wdec^T + bdec ; A = h2 history slots 1..64 */
    dim3 gD(V_ / 128, TB_ / 192);  // 250 x 16
    gemm_bias_kernel<<<gD, 256, 0, stream>>>(Hhi + (size_t)(2 * 65 + 1) * HB,
                                             Hlo + (size_t)(2 * 65 + 1) * HB, H_,
                                             Wdec, H_, H_, H_ / 32,
                                             bdec, nullptr, decoded, V_);
}